// Round 1
// 450.245 us; speedup vs baseline: 1.0102x; 1.0102x over previous
//
#include <hip/hip_runtime.h>

// VectorQuantizer: z (32,64,64,64) fp32, embedding_w (2048,64) fp32.
// Outputs concat: quantized_out (32,64,64,64) | indices (32,64,64) as float | loss (1)
//
// Numerics: bit-exact replication of the fp32 reference (verified prior session):
//   S_n = pairwise64(z_n^2), b_k = pairwise64(w_k^2)  (numpy pairwise_sum order)
//   C_nk = one sequential fp32 fused-FMA chain over c=0..63 ascending per (n,k)
//   d = fp32(fp32(S + b) - fp32(2*C)), argmin first-index tie-break.
//
// R5: (1) inner product issued as inline-asm v_pk_fma_f32 (2 rows packed per
// lane) with the w operand taken DIRECTLY from the s_loaded SGPR pair
// (w[c],w[c+1]) using op_sel broadcast -> no splat movs, guaranteed packed
// rate; per-half is a single fused fp32 FMA, ascending dims, so the chain is
// bit-identical. (2) tile halved to 128 rows -> LDS 35.4KB -> 4 blocks/CU
// (16 waves/CU) for latency hiding. (3) code sweep widened to 16 (acc[16])
// halving LDS re-reads. Loss partials in double (order-insensitive below
// fp32 ulp).

#define KCODES   2048
#define CDIM     64
#define OUT_Q    0
#define OUT_IDX  8388608
#define OUT_LOSS 8519680
#define PSTR     132        // floats per pair-row: 64 dims * 2 + 4 pad

typedef float f2 __attribute__((ext_vector_type(2)));
typedef unsigned long long u64;

// acc(lo,hi) += a(lo,hi) * splat(w.word0)   -- one fused fp32 FMA per half
__device__ __forceinline__ void pkfma_lo(f2& acc, f2 a, u64 w) {
    asm("v_pk_fma_f32 %0, %1, %2, %0 op_sel:[0,0,0] op_sel_hi:[1,0,1]"
        : "+v"(acc) : "v"(a), "s"(w));
}
// acc(lo,hi) += a(lo,hi) * splat(w.word1)
__device__ __forceinline__ void pkfma_hi(f2& acc, f2 a, u64 w) {
    asm("v_pk_fma_f32 %0, %1, %2, %0 op_sel:[0,1,0] op_sel_hi:[1,1,1]"
        : "+v"(acc) : "v"(a), "s"(w));
}

__device__ __forceinline__ float pairwise64(const float a[64]) {
    float r[8];
#pragma unroll
    for (int j = 0; j < 8; ++j) r[j] = a[j];
#pragma unroll
    for (int m = 1; m < 8; ++m)
#pragma unroll
        for (int j = 0; j < 8; ++j) r[j] = __fadd_rn(r[j], a[m * 8 + j]);
    float s01 = __fadd_rn(r[0], r[1]);
    float s23 = __fadd_rn(r[2], r[3]);
    float s45 = __fadd_rn(r[4], r[5]);
    float s67 = __fadd_rn(r[6], r[7]);
    return __fadd_rn(__fadd_rn(s01, s23), __fadd_rn(s45, s67));
}

__device__ __forceinline__ float fc(const float4& v, int i) {
    return i == 0 ? v.x : (i == 1 ? v.y : (i == 2 ? v.z : v.w));
}

// ---------------- kernel A: b_k = pairwise64(w_k^2) ----------------
__global__ __launch_bounds__(256) void vq_bsum(const float* __restrict__ w,
                                               float* __restrict__ bsum) {
    int k = blockIdx.x * 256 + threadIdx.x;
    const float4* wr = (const float4*)(w + (size_t)k * CDIM);
    float a[64];
#pragma unroll
    for (int m = 0; m < 16; ++m) {
        float4 v = wr[m];
        a[4 * m + 0] = __fmul_rn(v.x, v.x);
        a[4 * m + 1] = __fmul_rn(v.y, v.y);
        a[4 * m + 2] = __fmul_rn(v.z, v.z);
        a[4 * m + 3] = __fmul_rn(v.w, v.w);
    }
    bsum[k] = pairwise64(a);
}

// ---------------- kernel B: main VQ (fused argmin + epilogue) ----------------
__global__ __launch_bounds__(256, 4) void vq_main(const float* __restrict__ z,
                                                  const float* __restrict__ w,
                                                  const float* __restrict__ bsum,
                                                  float* __restrict__ out,
                                                  double* __restrict__ partial) {
    __shared__ float zsh[64 * PSTR];                // 33.8 KB: zsh[pair][dim] as float2
    __shared__ float Ss[128];
    __shared__ unsigned long long skey[128];
    __shared__ double lred[4];

    const int t  = threadIdx.x;
    const int l  = t & 63;                          // lane
    const int bb = blockIdx.x;                      // 0..1023; rows [bb*128, bb*128+128)
    const size_t zbase = (size_t)(bb >> 5) * 262144 + (size_t)(bb & 31) * 128;

    // ---- stage z tile: zsh[p][c] = (z_row{2p}_c, z_row{2p+1}_c) ----
#pragma unroll
    for (int m = 0; m < 16; ++m) {
        int i = m * 256 + t;                        // 0..4095
        int p = i & 63;
        int c = i >> 6;
        f2 v = *(const f2*)(z + zbase + (size_t)c * 4096 + 2 * p);
        *(f2*)&zsh[p * PSTR + 2 * c] = v;
    }
    __syncthreads();

    // ---- S per row (numpy pairwise of squares); init argmin keys ----
    if (t < 128) {
        float a[64];
        const int pb = (t >> 1) * PSTR + (t & 1);
#pragma unroll
        for (int c = 0; c < 64; ++c) {
            float v = zsh[pb + 2 * c];
            a[c] = __fmul_rn(v, v);
        }
        Ss[t] = pairwise64(a);
        skey[t] = 0xFFFFFFFFFFFFFFFFull;
    }
    __syncthreads();

    f2 Sp;
    Sp.x = Ss[2 * l]; Sp.y = Ss[2 * l + 1];

    // wave-uniform code range: wave wv handles codes [wv*512, wv*512+512)
    const int kwave = __builtin_amdgcn_readfirstlane(t >> 6) * 512;

    float dmin0 = __builtin_inff(), dmin1 = dmin0;
    int   kmin0 = 0, kmin1 = 0;
    const int zoffA = l * PSTR;

    for (int ks = 0; ks < 32; ++ks) {
        const int k0 = kwave + ks * 16;             // wave-uniform
        const float* wk = w + (size_t)k0 * CDIM;

        f2 acc[16];
#pragma unroll
        for (int j = 0; j < 16; ++j) acc[j] = (f2)0.f;

#pragma unroll 2
        for (int c0 = 0; c0 < 64; c0 += 4) {
            // z row-pair, dims c0..c0+3
            float4 a0 = *(const float4*)&zsh[zoffA + 2 * c0];
            float4 a1 = *(const float4*)&zsh[zoffA + 2 * c0 + 4];
            f2 aL0; aL0.x = a0.x; aL0.y = a0.y;     // pair @ c0
            f2 aH0; aH0.x = a0.z; aH0.y = a0.w;     // pair @ c0+1
            f2 aL1; aL1.x = a1.x; aL1.y = a1.y;     // pair @ c0+2
            f2 aH1; aH1.x = a1.z; aH1.y = a1.w;     // pair @ c0+3
#pragma unroll
            for (int j = 0; j < 16; ++j) {
                // wave-uniform address -> s_load (scalar pipe); word pairs
                u64 wp01 = *(const u64*)(wk + (size_t)j * CDIM + c0);
                u64 wp23 = *(const u64*)(wk + (size_t)j * CDIM + c0 + 2);
                // dims ascending -> sequential fused chain per (row, code)
                pkfma_lo(acc[j], aL0, wp01);        // * w[c0]
                pkfma_hi(acc[j], aH0, wp01);        // * w[c0+1]
                pkfma_lo(acc[j], aL1, wp23);        // * w[c0+2]
                pkfma_hi(acc[j], aH1, wp23);        // * w[c0+3]
            }
        }

        // d = fp32((S + b) - 2*C); strict < keeps earliest k (k ascending)
        const float4 bq0 = *(const float4*)(bsum + k0);      // uniform -> s_load
        const float4 bq1 = *(const float4*)(bsum + k0 + 4);
        const float4 bq2 = *(const float4*)(bsum + k0 + 8);
        const float4 bq3 = *(const float4*)(bsum + k0 + 12);
#pragma unroll
        for (int j = 0; j < 16; ++j) {
            float bj = (j < 4) ? fc(bq0, j) : (j < 8) ? fc(bq1, j - 4)
                     : (j < 12) ? fc(bq2, j - 8) : fc(bq3, j - 12);
            f2 bb2 = (f2)(bj);
            f2 dA = (Sp + bb2) - (acc[j] + acc[j]);
            int kg = k0 + j;
            if (dA.x < dmin0) { dmin0 = dA.x; kmin0 = kg; }
            if (dA.y < dmin1) { dmin1 = dA.y; kmin1 = kg; }
        }
    }

    // ---- merge per-row argmin across the 4 waves (packed key, LDS atomic) ----
    atomicMin(&skey[2 * l],     ((u64)__float_as_uint(dmin0) << 32) | (unsigned int)kmin0);
    atomicMin(&skey[2 * l + 1], ((u64)__float_as_uint(dmin1) << 32) | (unsigned int)kmin1);
    __syncthreads();

    // ---- epilogue: thread t owns row t&127, dim-half t>>7 ----
    const int row = t & 127;
    const int h   = t >> 7;
    const int kq  = (int)(skey[row] & 0xFFFFFFFFull);
    if (h == 0) out[OUT_IDX + (size_t)bb * 128 + row] = (float)kq;

    const float* wq = w + (size_t)kq * CDIM;
    const int pb = (row >> 1) * PSTR + (row & 1);
    double lacc = 0.0;
#pragma unroll
    for (int cc = 0; cc < 32; ++cc) {
        int c = h * 32 + cc;
        float zv = zsh[pb + 2 * c];
        float q  = wq[c];
        float d1  = __fsub_rn(q, zv);               // quantized - zp
        float val = __fadd_rn(zv, d1);              // zp + (q - zp)
        out[OUT_Q + zbase + (size_t)c * 4096 + row] = val;
        lacc += (double)__fmul_rn(d1, d1);
    }

#pragma unroll
    for (int off = 1; off < 64; off <<= 1) lacc += __shfl_xor(lacc, off, 64);
    if ((t & 63) == 0) lred[t >> 6] = lacc;
    __syncthreads();
    if (t == 0) partial[bb] = lred[0] + lred[1] + lred[2] + lred[3];
}

// ---------------- kernel C: reduce loss partials (1024 doubles) ----------------
__global__ __launch_bounds__(256) void vq_loss(const double* __restrict__ partial,
                                               float* __restrict__ out) {
    int t = threadIdx.x;
    double s = partial[t] + partial[t + 256] + partial[t + 512] + partial[t + 768];
#pragma unroll
    for (int off = 1; off < 64; off <<= 1) s += __shfl_xor(s, off, 64);
    __shared__ double sr[4];
    if ((t & 63) == 0) sr[t >> 6] = s;
    __syncthreads();
    if (t == 0)
        out[OUT_LOSS] = (float)((sr[0] + sr[1] + sr[2] + sr[3]) * (0.25 / 8388608.0));
}

extern "C" void kernel_launch(void* const* d_in, const int* in_sizes, int n_in,
                              void* d_out, int out_size, void* d_ws, size_t ws_size,
                              hipStream_t stream) {
    (void)in_sizes; (void)n_in; (void)out_size; (void)ws_size;
    const float* z = (const float*)d_in[0];
    const float* w = (const float*)d_in[1];
    float* out     = (float*)d_out;

    float*  bsum    = (float*)d_ws;                  // 2048 floats (8 KB)
    double* partial = (double*)((char*)d_ws + 8192); // 1024 doubles (8 KB)

    vq_bsum<<<8, 256, 0, stream>>>(w, bsum);
    vq_main<<<1024, 256, 0, stream>>>(z, w, bsum, out, partial);
    vq_loss<<<1, 256, 0, stream>>>(partial, out);
}